// Round 5
// baseline (800.996 us; speedup 1.0000x reference)
//
#include <hip/hip_runtime.h>
#include <stdint.h>

// Problem constants
#define IN_F   4096
#define OUT_F  4096
#define M_ROWS 8192      // 4 * 2048
#define KT     (IN_F / 64)   // 64 K-tiles of BK=64

typedef __attribute__((ext_vector_type(8))) short  bf16x8;
typedef __attribute__((ext_vector_type(4))) float  f32x4;

__device__ __forceinline__ short f2bf(float f) {
    union { float f; uint32_t u; } v; v.f = f;
    uint32_t r = v.u + 0x7FFFu + ((v.u >> 16) & 1u);
    return (short)(r >> 16);
}

__device__ __forceinline__ void load_lds16(const void* gsrc, void* lds) {
    __builtin_amdgcn_global_load_lds(
        (const __attribute__((address_space(1))) uint32_t*)gsrc,
        (__attribute__((address_space(3))) uint32_t*)lds,
        16, 0, 0);
}

// ============================================================================
// Kernel 1: GPTQ dequant -> W^T bf16 [OUT_F][IN_F]
// ============================================================================
__global__ void dequant_wt_kernel(const int* __restrict__ qweight,
                                  const int* __restrict__ qzeros,
                                  const float* __restrict__ scales,
                                  short* __restrict__ wt)
{
    int t  = blockIdx.x * blockDim.x + threadIdx.x;
    int n  = t >> 9;
    int kw = t & 511;
    int g  = kw >> 4;

    float s = scales[g * OUT_F + n];
    uint32_t zw = (uint32_t)qzeros[g * (OUT_F / 8) + (n >> 3)];
    float z1 = (float)((zw >> (4 * (n & 7))) & 0xFu) + 1.0f;
    uint32_t q = (uint32_t)qweight[kw * OUT_F + n];

    bf16x8 out;
#pragma unroll
    for (int i = 0; i < 8; ++i) {
        float w = s * ((float)((q >> (4 * i)) & 0xFu) - z1);
        out[i] = f2bf(w);
    }
    *reinterpret_cast<bf16x8*>(&wt[(size_t)n * IN_F + kw * 8]) = out;
}

// ============================================================================
// Kernel 2: X fp32 -> bf16 prepass
// ============================================================================
__global__ void xconv_kernel(const float* __restrict__ x, short* __restrict__ xb)
{
    int t = blockIdx.x * blockDim.x + threadIdx.x;
    const float4* src = reinterpret_cast<const float4*>(x) + (size_t)t * 2;
    float4 a = src[0], b = src[1];
    bf16x8 h;
    h[0] = f2bf(a.x); h[1] = f2bf(a.y); h[2] = f2bf(a.z); h[3] = f2bf(a.w);
    h[4] = f2bf(b.x); h[5] = f2bf(b.y); h[6] = f2bf(b.z); h[7] = f2bf(b.w);
    reinterpret_cast<bf16x8*>(xb)[t] = h;
}

// ============================================================================
// Kernel 3: 256x256 GEMM — A via LDS (3-slot counted pipeline, T2 swizzle),
//           B DIRECT global->VGPR (prefetched 1 tile ahead; removes ~100KB/tile
//           of LDS traffic), XCD-swizzled 1D grid (T1).
//   Per tile t: issue B(t+1) regs [8 loads], A(t+2)->LDS [4 loads].
//   In-order vmcnt retire (m135): end-of-tile outstanding <= A(t+1)4 + 12 new
//   -> vmcnt(12) drains exactly A(t+1). t==KT-2: vmcnt(8). t==KT-1: none.
// ============================================================================
#define A_SLOT 32768

__global__ __launch_bounds__(512, 1) void gemm8_kernel(
    const short* __restrict__ Xb,   // [M_ROWS][IN_F] bf16
    const short* __restrict__ WT,   // [OUT_F][IN_F] bf16
    float* __restrict__ C)          // [M_ROWS][OUT_F]
{
    __shared__ short AsBuf[3 * 256 * 64];   // 96 KB
    char* const Abase = (char*)AsBuf;

    const int tid  = threadIdx.x;
    const int lane = tid & 63;
    const int wid  = tid >> 6;     // 0..7
    const int wr   = wid >> 2;     // 0..1  (M half)
    const int wc   = wid & 3;      // 0..3  (N quarter)

    // ---- T1: bijective XCD swizzle (512 blocks, 512%8==0)
    const int bid = blockIdx.x;
    const int swz = (bid & 7) * 64 + (bid >> 3);
    const int row0 = (swz >> 4) * 256;   // 32 row-tiles
    const int col0 = (swz & 15) * 256;   // 16 col-tiles

    // ---- A staging geometry (verified r2-r4): pre-swizzled global source,
    //      linear LDS dest (rule 21)
    const int rL0 = tid >> 3;
    const int csw = ((tid & 7) << 3) ^ ((rL0 & 7) << 3);
    const short* gA[4]; int dOff[4];
#pragma unroll
    for (int L = 0; L < 4; ++L) {
        gA[L] = Xb + (size_t)(row0 + L * 64 + rL0) * IN_F + csw;
        dOff[L] = L * 8192 + tid * 16;
    }

    // ---- A read geometry (verified): frag(ks) at byte k0 ^ (ks<<6)
    const int frow = lane & 15;
    const int k0   = ((lane >> 4) << 4) ^ ((frow & 7) << 4);

    // ---- B direct-load geometry: same bytes/regs as the old ds_read path
    const short* gBf = WT + (size_t)(col0 + wc * 64 + frow) * IN_F + ((lane >> 4) << 3);

    f32x4 acc[8][4] = {};
    bf16x8 B0[8], B1[8];    // [n*2+ks], two named sets (rule 20)

    // ---- prologue: A(0)->slot0 [4], B(0) [8], A(1)->slot1 [4]
#pragma unroll
    for (int L = 0; L < 4; ++L) load_lds16(gA[L], Abase + 0 * A_SLOT + dOff[L]);
#pragma unroll
    for (int n = 0; n < 4; ++n) {
        const short* p = gBf + (size_t)n * 16 * IN_F;
        B0[n * 2]     = *reinterpret_cast<const bf16x8*>(p);
        B0[n * 2 + 1] = *reinterpret_cast<const bf16x8*>(p + 32);
    }
#pragma unroll
    for (int L = 0; L < 4; ++L) load_lds16(gA[L] + 64, Abase + 1 * A_SLOT + dOff[L]);
    asm volatile("s_waitcnt vmcnt(12)" ::: "memory");   // drains A(0); B0 via reg deps
    __builtin_amdgcn_s_barrier();

    int sA  = 0;   // t % 3
    int sA2 = 2;   // (t+2) % 3

    auto body = [&](int t, bf16x8 (&Bcur)[8], bf16x8 (&Bnxt)[8]) {
        char* Ab = Abase + sA * A_SLOT;

        // -- B(t+1) -> regs (8 global_load_dwordx4, L2-resident panel)
        if (t + 1 < KT) {
#pragma unroll
            for (int n = 0; n < 4; ++n) {
                const short* p = gBf + (size_t)n * 16 * IN_F + (size_t)(t + 1) * 64;
                Bnxt[n * 2]     = *reinterpret_cast<const bf16x8*>(p);
                Bnxt[n * 2 + 1] = *reinterpret_cast<const bf16x8*>(p + 32);
            }
        }
        // -- A(t+2) -> LDS slot (t+2)%3
        if (t + 2 < KT) {
            char* An = Abase + sA2 * A_SLOT;
#pragma unroll
            for (int L = 0; L < 4; ++L)
                load_lds16(gA[L] + (size_t)(t + 2) * 64, An + dOff[L]);
        }

#pragma unroll
        for (int ks = 0; ks < 2; ++ks) {
            const int kb = k0 ^ (ks << 6);
            bf16x8 af[8];
#pragma unroll
            for (int m = 0; m < 8; ++m) {
                const int r = wr * 128 + m * 16 + frow;
                af[m] = *reinterpret_cast<const bf16x8*>(Ab + r * 128 + kb);
            }
            __builtin_amdgcn_s_setprio(1);
#pragma unroll
            for (int m = 0; m < 8; ++m)
#pragma unroll
                for (int n = 0; n < 4; ++n)
                    acc[m][n] = __builtin_amdgcn_mfma_f32_16x16x32_bf16(
                        af[m], Bcur[n * 2 + ks], acc[m][n], 0, 0, 0);
            __builtin_amdgcn_s_setprio(0);
        }

        if (t < KT - 2)       asm volatile("s_waitcnt vmcnt(12)" ::: "memory");
        else if (t == KT - 2) asm volatile("s_waitcnt vmcnt(8)"  ::: "memory");
        if (t < KT - 1) __builtin_amdgcn_s_barrier();

        sA  = (sA  < 2) ? sA  + 1 : 0;
        sA2 = (sA2 < 2) ? sA2 + 1 : 0;
    };

    for (int t = 0; t < KT; t += 2) {   // KT even; named-set rotation (rule 20)
        body(t,     B0, B1);
        body(t + 1, B1, B0);
    }

    // ---- epilogue: C/D layout col=lane&15, row=(lane>>4)*4+reg (verified)
    const int crow = (lane >> 4) * 4;
    const int ccol = lane & 15;
#pragma unroll
    for (int fm = 0; fm < 8; ++fm)
#pragma unroll
        for (int fn = 0; fn < 4; ++fn)
#pragma unroll
            for (int r = 0; r < 4; ++r) {
                const int row = row0 + wr * 128 + fm * 16 + crow + r;
                const int col = col0 + wc * 64 + fn * 16 + ccol;
                C[(size_t)row * OUT_F + col] = acc[fm][fn][r];
            }
}

// ============================================================================
// Fallback GEMM (round-1, verified): used only if ws too small for Xb
// ============================================================================
#define BM 128
#define BN 128
#define BK 64

__global__ __launch_bounds__(256, 2) void gemm_x_wt_kernel(
    const float* __restrict__ X,
    const short* __restrict__ WT,
    float* __restrict__ C)
{
    __shared__ short As2[BM * BK];
    __shared__ short Bs2[BN * BK];

    const int bn = blockIdx.x;
    const int bm = blockIdx.y;
    const int tid  = threadIdx.x;
    const int lane = tid & 63;
    const int wid  = tid >> 6;
    const int wr   = wid >> 1;
    const int wc   = wid & 1;

    const int row0 = bm * BM;
    const int col0 = bn * BN;
    const int frow = lane & 15;
    const int fk   = (lane >> 4) * 8;

    f32x4 acc[4][4] = {};

    for (int kt = 0; kt < IN_F / BK; ++kt) {
        float4 a0[4], a1[4];
#pragma unroll
        for (int j = 0; j < 4; ++j) {
            const int flat = (j * 256 + tid) * 8;
            const int r = flat >> 6;
            const int c = flat & (BK - 1);
            const float* src = X + (size_t)(row0 + r) * IN_F + kt * BK + c;
            a0[j] = *reinterpret_cast<const float4*>(src);
            a1[j] = *reinterpret_cast<const float4*>(src + 4);
        }
        __syncthreads();
#pragma unroll
        for (int j = 0; j < 4; ++j) {
            const int flat = (j * 256 + tid) * 8;
            const int r = flat >> 6;
            const int c = flat & (BK - 1);
            load_lds16(WT + (size_t)(col0 + r) * IN_F + kt * BK + c, &Bs2[flat]);
        }
#pragma unroll
        for (int j = 0; j < 4; ++j) {
            const int flat = (j * 256 + tid) * 8;
            bf16x8 h;
            h[0] = f2bf(a0[j].x); h[1] = f2bf(a0[j].y);
            h[2] = f2bf(a0[j].z); h[3] = f2bf(a0[j].w);
            h[4] = f2bf(a1[j].x); h[5] = f2bf(a1[j].y);
            h[6] = f2bf(a1[j].z); h[7] = f2bf(a1[j].w);
            *reinterpret_cast<bf16x8*>(&As2[flat]) = h;
        }
        __syncthreads();
#pragma unroll
        for (int s = 0; s < 2; ++s) {
            bf16x8 af[4], bfr[4];
#pragma unroll
            for (int m = 0; m < 4; ++m) {
                const int row = wr * 64 + m * 16 + frow;
                af[m] = *reinterpret_cast<const bf16x8*>(&As2[row * BK + s * 32 + fk]);
            }
#pragma unroll
            for (int n = 0; n < 4; ++n) {
                const int col = wc * 64 + n * 16 + frow;
                bfr[n] = *reinterpret_cast<const bf16x8*>(&Bs2[col * BK + s * 32 + fk]);
            }
#pragma unroll
            for (int m = 0; m < 4; ++m)
#pragma unroll
                for (int n = 0; n < 4; ++n)
                    acc[m][n] = __builtin_amdgcn_mfma_f32_16x16x32_bf16(
                        af[m], bfr[n], acc[m][n], 0, 0, 0);
        }
    }

    const int crow = (lane >> 4) * 4;
    const int ccol = lane & 15;
#pragma unroll
    for (int m = 0; m < 4; ++m)
#pragma unroll
        for (int n = 0; n < 4; ++n)
#pragma unroll
            for (int r = 0; r < 4; ++r) {
                const int row = row0 + wr * 64 + m * 16 + crow + r;
                const int col = col0 + wc * 64 + n * 16 + ccol;
                C[(size_t)row * OUT_F + col] = acc[m][n][r];
            }
}

// ============================================================================
extern "C" void kernel_launch(void* const* d_in, const int* in_sizes, int n_in,
                              void* d_out, int out_size, void* d_ws, size_t ws_size,
                              hipStream_t stream) {
    const float* x       = (const float*)d_in[0];
    const int*   qweight = (const int*)  d_in[1];
    const int*   qzeros  = (const int*)  d_in[2];
    const float* scales  = (const float*)d_in[3];
    float*       out     = (float*)d_out;

    const size_t WT_BYTES = (size_t)OUT_F * IN_F * 2;   // 33.5 MB
    const size_t XB_BYTES = (size_t)M_ROWS * IN_F * 2;  // 67.1 MB

    short* wt = (short*)d_ws;

    dequant_wt_kernel<<<(OUT_F * (IN_F / 8)) / 256, 256, 0, stream>>>(
        qweight, qzeros, scales, wt);

    if (ws_size >= WT_BYTES + XB_BYTES) {
        short* xb = (short*)((char*)d_ws + WT_BYTES);
        xconv_kernel<<<(M_ROWS * IN_F / 8) / 256, 256, 0, stream>>>(x, xb);
        gemm8_kernel<<<(M_ROWS / 256) * (OUT_F / 256), 512, 0, stream>>>(xb, wt, out);
    } else {
        dim3 grid(OUT_F / BN, M_ROWS / BM);
        gemm_x_wt_kernel<<<grid, 256, 0, stream>>>(x, wt, out);
    }
}

// Round 6
// 769.880 us; speedup vs baseline: 1.0404x; 1.0404x over previous
//
#include <hip/hip_runtime.h>
#include <stdint.h>

// Problem constants
#define IN_F   4096
#define OUT_F  4096
#define M_ROWS 8192      // 4 * 2048
#define KT     (IN_F / 64)   // 64 K-tiles of BK=64

typedef __attribute__((ext_vector_type(8))) short  bf16x8;
typedef __attribute__((ext_vector_type(4))) float  f32x4;

__device__ __forceinline__ short f2bf(float f) {
    union { float f; uint32_t u; } v; v.f = f;
    uint32_t r = v.u + 0x7FFFu + ((v.u >> 16) & 1u);
    return (short)(r >> 16);
}

__device__ __forceinline__ void load_lds16(const void* gsrc, void* lds) {
    __builtin_amdgcn_global_load_lds(
        (const __attribute__((address_space(1))) uint32_t*)gsrc,
        (__attribute__((address_space(3))) uint32_t*)lds,
        16, 0, 0);
}

// ============================================================================
// Kernel 1: GPTQ dequant -> W^T bf16 [OUT_F][IN_F]
// ============================================================================
__global__ void dequant_wt_kernel(const int* __restrict__ qweight,
                                  const int* __restrict__ qzeros,
                                  const float* __restrict__ scales,
                                  short* __restrict__ wt)
{
    int t  = blockIdx.x * blockDim.x + threadIdx.x;
    int n  = t >> 9;
    int kw = t & 511;
    int g  = kw >> 4;

    float s = scales[g * OUT_F + n];
    uint32_t zw = (uint32_t)qzeros[g * (OUT_F / 8) + (n >> 3)];
    float z1 = (float)((zw >> (4 * (n & 7))) & 0xFu) + 1.0f;
    uint32_t q = (uint32_t)qweight[kw * OUT_F + n];

    bf16x8 out;
#pragma unroll
    for (int i = 0; i < 8; ++i) {
        float w = s * ((float)((q >> (4 * i)) & 0xFu) - z1);
        out[i] = f2bf(w);
    }
    *reinterpret_cast<bf16x8*>(&wt[(size_t)n * IN_F + kw * 8]) = out;
}

// ============================================================================
// Kernel 2: X fp32 -> bf16 prepass
// ============================================================================
__global__ void xconv_kernel(const float* __restrict__ x, short* __restrict__ xb)
{
    int t = blockIdx.x * blockDim.x + threadIdx.x;
    const float4* src = reinterpret_cast<const float4*>(x) + (size_t)t * 2;
    float4 a = src[0], b = src[1];
    bf16x8 h;
    h[0] = f2bf(a.x); h[1] = f2bf(a.y); h[2] = f2bf(a.z); h[3] = f2bf(a.w);
    h[4] = f2bf(b.x); h[5] = f2bf(b.y); h[6] = f2bf(b.z); h[7] = f2bf(b.w);
    reinterpret_cast<bf16x8*>(xb)[t] = h;
}

// ============================================================================
// Kernel 3: 256x256 GEMM.
//   A: LDS 3-slot counted pipeline + T2 swizzle (verified r2-r4, 0 conflicts).
//   B: DIRECT global->VGPR, prefetched 1 K-tile ahead into alternating NAMED
//      sets B0/B1 (macro-expanded body, literal indices only — rule 20; the
//      r5 lambda caused a 128-VGPR cap + full spill).
//   Removes B's 96KB/tile of LDS traffic -> LDS ~241K cy < MFMA ~264K cy/CU.
//   vmcnt ledger (in-order retire): per tile issue B(t+1)[8] then A(t+2)[4];
//   end-of-tile outstanding = A(t+1)4 + B(t+1)8 + A(t+2)4 = 16 -> vmcnt(4)
//   drains A(t+1),B(t+1), keeps A(t+2) in flight. t==KT-2 -> vmcnt(0).
// ============================================================================
#define A_SLOT 32768

#define GTILE(T, BCUR, BNXT)                                                   \
    {                                                                          \
        char* Ab = Abase + sA * A_SLOT;                                        \
        if ((T) + 1 < KT) {                                                    \
            _Pragma("unroll")                                                  \
            for (int n = 0; n < 4; ++n) {                                      \
                const short* p = gBf + (size_t)n * 16 * IN_F                   \
                                     + (size_t)((T) + 1) * 64;                 \
                BNXT[n * 2]     = *reinterpret_cast<const bf16x8*>(p);         \
                BNXT[n * 2 + 1] = *reinterpret_cast<const bf16x8*>(p + 32);    \
            }                                                                  \
        }                                                                      \
        if ((T) + 2 < KT) {                                                    \
            char* An = Abase + sA2 * A_SLOT;                                   \
            _Pragma("unroll")                                                  \
            for (int L = 0; L < 4; ++L)                                        \
                load_lds16(gA[L] + (size_t)((T) + 2) * 64, An + dOff[L]);      \
        }                                                                      \
        _Pragma("unroll")                                                      \
        for (int ks = 0; ks < 2; ++ks) {                                       \
            const int kb = k0 ^ (ks << 6);                                     \
            bf16x8 af[8];                                                      \
            _Pragma("unroll")                                                  \
            for (int m = 0; m < 8; ++m) {                                      \
                const int r = wr * 128 + m * 16 + frow;                        \
                af[m] = *reinterpret_cast<const bf16x8*>(Ab + r * 128 + kb);   \
            }                                                                  \
            __builtin_amdgcn_s_setprio(1);                                     \
            _Pragma("unroll")                                                  \
            for (int m = 0; m < 8; ++m) {                                      \
                acc[m][0] = __builtin_amdgcn_mfma_f32_16x16x32_bf16(           \
                    af[m], BCUR[0 + ks], acc[m][0], 0, 0, 0);                  \
                acc[m][1] = __builtin_amdgcn_mfma_f32_16x16x32_bf16(           \
                    af[m], BCUR[2 + ks], acc[m][1], 0, 0, 0);                  \
                acc[m][2] = __builtin_amdgcn_mfma_f32_16x16x32_bf16(           \
                    af[m], BCUR[4 + ks], acc[m][2], 0, 0, 0);                  \
                acc[m][3] = __builtin_amdgcn_mfma_f32_16x16x32_bf16(           \
                    af[m], BCUR[6 + ks], acc[m][3], 0, 0, 0);                  \
            }                                                                  \
            __builtin_amdgcn_s_setprio(0);                                     \
        }                                                                      \
        if ((T) < KT - 2)                                                      \
            asm volatile("s_waitcnt vmcnt(4)" ::: "memory");                   \
        else if ((T) == KT - 2)                                                \
            asm volatile("s_waitcnt vmcnt(0)" ::: "memory");                   \
        if ((T) < KT - 1) __builtin_amdgcn_s_barrier();                        \
        sA  = (sA  < 2) ? sA  + 1 : 0;                                        \
        sA2 = (sA2 < 2) ? sA2 + 1 : 0;                                        \
    }

__global__ __launch_bounds__(512, 2) void gemm8_kernel(
    const short* __restrict__ Xb,   // [M_ROWS][IN_F] bf16
    const short* __restrict__ WT,   // [OUT_F][IN_F] bf16
    float* __restrict__ C)          // [M_ROWS][OUT_F]
{
    __shared__ short AsBuf[3 * 256 * 64];   // 96 KB
    char* const Abase = (char*)AsBuf;

    const int tid  = threadIdx.x;
    const int lane = tid & 63;
    const int wid  = tid >> 6;     // 0..7
    const int wr   = wid >> 2;     // 0..1  (M half)
    const int wc   = wid & 3;      // 0..3  (N quarter)

    const int row0 = blockIdx.y * 256;
    const int col0 = blockIdx.x * 256;

    // ---- A staging geometry (verified r2-r4): pre-swizzled global source,
    //      linear LDS dest (rule 21)
    const int rL0 = tid >> 3;
    const int csw = ((tid & 7) << 3) ^ ((rL0 & 7) << 3);
    const short* gA[4]; int dOff[4];
#pragma unroll
    for (int L = 0; L < 4; ++L) {
        gA[L] = Xb + (size_t)(row0 + L * 64 + rL0) * IN_F + csw;
        dOff[L] = L * 8192 + tid * 16;
    }

    // ---- A read geometry (verified): frag(ks) at byte k0 ^ (ks<<6)
    const int frow = lane & 15;
    const int k0   = ((lane >> 4) << 4) ^ ((frow & 7) << 4);

    // ---- B direct-load geometry (fragment mapping validated in r5):
    //      lane reads WT[col0 + wc*64 + n*16 + (lane&15)][t*64 + (lane>>4)*8 (+32*ks)]
    const short* gBf = WT + (size_t)(col0 + wc * 64 + frow) * IN_F + ((lane >> 4) << 3);

    f32x4 acc[8][4] = {};
    bf16x8 B0[8], B1[8];    // [n*2+ks], named sets, literal indices only

    // ---- prologue: A(0)->s0 [4], B(0)->B0 [8], A(1)->s1 [4]; vmcnt(4)
#pragma unroll
    for (int L = 0; L < 4; ++L) load_lds16(gA[L], Abase + 0 * A_SLOT + dOff[L]);
#pragma unroll
    for (int n = 0; n < 4; ++n) {
        const short* p = gBf + (size_t)n * 16 * IN_F;
        B0[n * 2]     = *reinterpret_cast<const bf16x8*>(p);
        B0[n * 2 + 1] = *reinterpret_cast<const bf16x8*>(p + 32);
    }
#pragma unroll
    for (int L = 0; L < 4; ++L) load_lds16(gA[L] + 64, Abase + 1 * A_SLOT + dOff[L]);
    asm volatile("s_waitcnt vmcnt(4)" ::: "memory");
    __builtin_amdgcn_s_barrier();

    int sA  = 0;   // t % 3
    int sA2 = 2;   // (t+2) % 3

    for (int t = 0; t < KT; t += 2) {   // KT even
        GTILE(t,     B0, B1)
        GTILE(t + 1, B1, B0)
    }

    // ---- epilogue: C/D layout col=lane&15, row=(lane>>4)*4+reg (verified)
    const int crow = (lane >> 4) * 4;
    const int ccol = lane & 15;
#pragma unroll
    for (int fm = 0; fm < 8; ++fm)
#pragma unroll
        for (int fn = 0; fn < 4; ++fn)
#pragma unroll
            for (int r = 0; r < 4; ++r) {
                const int row = row0 + wr * 128 + fm * 16 + crow + r;
                const int col = col0 + wc * 64 + fn * 16 + ccol;
                C[(size_t)row * OUT_F + col] = acc[fm][fn][r];
            }
}

// ============================================================================
// Fallback GEMM (round-1, verified): used only if ws too small for Xb
// ============================================================================
#define BM 128
#define BN 128
#define BK 64

__global__ __launch_bounds__(256, 2) void gemm_x_wt_kernel(
    const float* __restrict__ X,
    const short* __restrict__ WT,
    float* __restrict__ C)
{
    __shared__ short As2[BM * BK];
    __shared__ short Bs2[BN * BK];

    const int bn = blockIdx.x;
    const int bm = blockIdx.y;
    const int tid  = threadIdx.x;
    const int lane = tid & 63;
    const int wid  = tid >> 6;
    const int wr   = wid >> 1;
    const int wc   = wid & 1;

    const int row0 = bm * BM;
    const int col0 = bn * BN;
    const int frow = lane & 15;
    const int fk   = (lane >> 4) * 8;

    f32x4 acc[4][4] = {};

    for (int kt = 0; kt < IN_F / BK; ++kt) {
        float4 a0[4], a1[4];
#pragma unroll
        for (int j = 0; j < 4; ++j) {
            const int flat = (j * 256 + tid) * 8;
            const int r = flat >> 6;
            const int c = flat & (BK - 1);
            const float* src = X + (size_t)(row0 + r) * IN_F + kt * BK + c;
            a0[j] = *reinterpret_cast<const float4*>(src);
            a1[j] = *reinterpret_cast<const float4*>(src + 4);
        }
        __syncthreads();
#pragma unroll
        for (int j = 0; j < 4; ++j) {
            const int flat = (j * 256 + tid) * 8;
            const int r = flat >> 6;
            const int c = flat & (BK - 1);
            load_lds16(WT + (size_t)(col0 + r) * IN_F + kt * BK + c, &Bs2[flat]);
        }
#pragma unroll
        for (int j = 0; j < 4; ++j) {
            const int flat = (j * 256 + tid) * 8;
            bf16x8 h;
            h[0] = f2bf(a0[j].x); h[1] = f2bf(a0[j].y);
            h[2] = f2bf(a0[j].z); h[3] = f2bf(a0[j].w);
            h[4] = f2bf(a1[j].x); h[5] = f2bf(a1[j].y);
            h[6] = f2bf(a1[j].z); h[7] = f2bf(a1[j].w);
            *reinterpret_cast<bf16x8*>(&As2[flat]) = h;
        }
        __syncthreads();
#pragma unroll
        for (int s = 0; s < 2; ++s) {
            bf16x8 af[4], bfr[4];
#pragma unroll
            for (int m = 0; m < 4; ++m) {
                const int row = wr * 64 + m * 16 + frow;
                af[m] = *reinterpret_cast<const bf16x8*>(&As2[row * BK + s * 32 + fk]);
            }
#pragma unroll
            for (int n = 0; n < 4; ++n) {
                const int col = wc * 64 + n * 16 + frow;
                bfr[n] = *reinterpret_cast<const bf16x8*>(&Bs2[col * BK + s * 32 + fk]);
            }
#pragma unroll
            for (int m = 0; m < 4; ++m)
#pragma unroll
                for (int n = 0; n < 4; ++n)
                    acc[m][n] = __builtin_amdgcn_mfma_f32_16x16x32_bf16(
                        af[m], bfr[n], acc[m][n], 0, 0, 0);
        }
    }

    const int crow = (lane >> 4) * 4;
    const int ccol = lane & 15;
#pragma unroll
    for (int m = 0; m < 4; ++m)
#pragma unroll
        for (int n = 0; n < 4; ++n)
#pragma unroll
            for (int r = 0; r < 4; ++r) {
                const int row = row0 + wr * 64 + m * 16 + crow + r;
                const int col = col0 + wc * 64 + n * 16 + ccol;
                C[(size_t)row * OUT_F + col] = acc[m][n][r];
            }
}

// ============================================================================
extern "C" void kernel_launch(void* const* d_in, const int* in_sizes, int n_in,
                              void* d_out, int out_size, void* d_ws, size_t ws_size,
                              hipStream_t stream) {
    const float* x       = (const float*)d_in[0];
    const int*   qweight = (const int*)  d_in[1];
    const int*   qzeros  = (const int*)  d_in[2];
    const float* scales  = (const float*)d_in[3];
    float*       out     = (float*)d_out;

    const size_t WT_BYTES = (size_t)OUT_F * IN_F * 2;   // 33.5 MB
    const size_t XB_BYTES = (size_t)M_ROWS * IN_F * 2;  // 67.1 MB

    short* wt = (short*)d_ws;

    dequant_wt_kernel<<<(OUT_F * (IN_F / 8)) / 256, 256, 0, stream>>>(
        qweight, qzeros, scales, wt);

    if (ws_size >= WT_BYTES + XB_BYTES) {
        short* xb = (short*)((char*)d_ws + WT_BYTES);
        xconv_kernel<<<(M_ROWS * IN_F / 8) / 256, 256, 0, stream>>>(x, xb);
        dim3 grid(OUT_F / 256, M_ROWS / 256);   // (16, 32)
        gemm8_kernel<<<grid, 512, 0, stream>>>(xb, wt, out);
    } else {
        dim3 grid(OUT_F / BN, M_ROWS / BM);
        gemm_x_wt_kernel<<<grid, 256, 0, stream>>>(x, wt, out);
    }
}

// Round 7
// 416.930 us; speedup vs baseline: 1.9212x; 1.8465x over previous
//
#include <hip/hip_runtime.h>
#include <stdint.h>

// Problem constants
#define IN_F   4096
#define OUT_F  4096
#define M_ROWS 8192      // 4 * 2048
#define KT     (IN_F / 64)   // 64 K-tiles of BK=64

typedef __attribute__((ext_vector_type(8))) short  bf16x8;
typedef __attribute__((ext_vector_type(4))) float  f32x4;

__device__ __forceinline__ short f2bf(float f) {
    union { float f; uint32_t u; } v; v.f = f;
    uint32_t r = v.u + 0x7FFFu + ((v.u >> 16) & 1u);
    return (short)(r >> 16);
}

__device__ __forceinline__ void load_lds16(const void* gsrc, void* lds) {
    __builtin_amdgcn_global_load_lds(
        (const __attribute__((address_space(1))) uint32_t*)gsrc,
        (__attribute__((address_space(3))) uint32_t*)lds,
        16, 0, 0);
}

// ============================================================================
// Kernel 1: GPTQ dequant -> W^T bf16 [OUT_F][IN_F]
// ============================================================================
__global__ void dequant_wt_kernel(const int* __restrict__ qweight,
                                  const int* __restrict__ qzeros,
                                  const float* __restrict__ scales,
                                  short* __restrict__ wt)
{
    int t  = blockIdx.x * blockDim.x + threadIdx.x;
    int n  = t >> 9;
    int kw = t & 511;
    int g  = kw >> 4;

    float s = scales[g * OUT_F + n];
    uint32_t zw = (uint32_t)qzeros[g * (OUT_F / 8) + (n >> 3)];
    float z1 = (float)((zw >> (4 * (n & 7))) & 0xFu) + 1.0f;
    uint32_t q = (uint32_t)qweight[kw * OUT_F + n];

    bf16x8 out;
#pragma unroll
    for (int i = 0; i < 8; ++i) {
        float w = s * ((float)((q >> (4 * i)) & 0xFu) - z1);
        out[i] = f2bf(w);
    }
    *reinterpret_cast<bf16x8*>(&wt[(size_t)n * IN_F + kw * 8]) = out;
}

// ============================================================================
// Kernel 2: X fp32 -> bf16 prepass
// ============================================================================
__global__ void xconv_kernel(const float* __restrict__ x, short* __restrict__ xb)
{
    int t = blockIdx.x * blockDim.x + threadIdx.x;
    const float4* src = reinterpret_cast<const float4*>(x) + (size_t)t * 2;
    float4 a = src[0], b = src[1];
    bf16x8 h;
    h[0] = f2bf(a.x); h[1] = f2bf(a.y); h[2] = f2bf(a.z); h[3] = f2bf(a.w);
    h[4] = f2bf(b.x); h[5] = f2bf(b.y); h[6] = f2bf(b.z); h[7] = f2bf(b.w);
    reinterpret_cast<bf16x8*>(xb)[t] = h;
}

// ============================================================================
// Kernel 3: 256x256 GEMM.
//   A: LDS 3-slot pipeline + T2 swizzle (verified r2-r4, 0 bank conflicts).
//   B: DIRECT global->VGPR, SINGLE-buffered Bc[8] (32 VGPR). B(t+1) is issued
//      AFTER the last MFMA use of B(t) (reg WAR keeps one set). The compiler's
//      own wait-for-B(t) before tile-t MFMAs is the counted vmcnt: since B(t)
//      was issued after A(t+1) (in tile t-1), B(t) retired => A(t+1) in LDS
//      (in-order vm retire, validated r5/r6); the end-of-tile barrier
//      publishes it. No per-tile explicit vmcnt; loads never drain to 0.
//   Reg budget (hard cap 256/wave at 8-wave blocks): acc 128 AGPR + ~100 VGPR.
//   T1: col-stripe XCD swizzle -> B panel 4MB/XCD stays L2-resident.
// ============================================================================
#define A_SLOT 32768

__global__ __launch_bounds__(512, 2) void gemm8_kernel(
    const short* __restrict__ Xb,   // [M_ROWS][IN_F] bf16
    const short* __restrict__ WT,   // [OUT_F][IN_F] bf16
    float* __restrict__ C)          // [M_ROWS][OUT_F]
{
    __shared__ short AsBuf[3 * 256 * 64];   // 96 KB
    char* const Abase = (char*)AsBuf;

    const int tid  = threadIdx.x;
    const int lane = tid & 63;
    const int wid  = tid >> 6;     // 0..7
    const int wr   = wid >> 2;     // 0..1  (M half)
    const int wc   = wid & 3;      // 0..3  (N quarter)

    // ---- T1 col-stripe: XCD (bid&7) owns output col-tiles {2*xcd, 2*xcd+1}
    //      (4 MB B panel per XCD -> L2-resident); rows sweep within the XCD.
    const int bid  = blockIdx.x;           // 0..511, 512%8==0 -> bijective
    const int xcd  = bid & 7;
    const int jj   = bid >> 3;             // 0..63
    const int col0 = (xcd * 2 + (jj & 1)) * 256;
    const int row0 = (jj >> 1) * 256;

    // ---- A staging geometry (verified r2-r4): pre-swizzled global source,
    //      linear LDS dest (rule 21)
    const int rL0 = tid >> 3;
    const int csw = ((tid & 7) << 3) ^ ((rL0 & 7) << 3);
    const short* gA[4]; int dOff[4];
#pragma unroll
    for (int L = 0; L < 4; ++L) {
        gA[L] = Xb + (size_t)(row0 + L * 64 + rL0) * IN_F + csw;
        dOff[L] = L * 8192 + tid * 16;
    }

    // ---- A read geometry (verified): frag(ks) at byte k0 ^ (ks<<6)
    const int frow = lane & 15;
    const int k0   = ((lane >> 4) << 4) ^ ((frow & 7) << 4);

    // ---- B direct-load geometry (mapping validated r5/r6: same bytes/regs
    //      as the old ds_read path): lane reads
    //      WT[col0 + wc*64 + n*16 + (lane&15)][t*64 + (lane>>4)*8 + 32*ks]
    const short* gBf = WT + (size_t)(col0 + wc * 64 + frow) * IN_F + ((lane >> 4) << 3);

    f32x4 acc[8][4] = {};
    bf16x8 Bc[8];           // [n*2+ks], single set, literal indices only

    // ---- prologue: A(0)->s0 [4], A(1)->s1 [4], B(0) [8]
    //      (B(0) AFTER A(1): B-retire implies A-retire invariant)
#pragma unroll
    for (int L = 0; L < 4; ++L) load_lds16(gA[L],      Abase + 0 * A_SLOT + dOff[L]);
#pragma unroll
    for (int L = 0; L < 4; ++L) load_lds16(gA[L] + 64, Abase + 1 * A_SLOT + dOff[L]);
#pragma unroll
    for (int n = 0; n < 4; ++n) {
        const short* p = gBf + (size_t)n * 16 * IN_F;
        Bc[n * 2]     = *reinterpret_cast<const bf16x8*>(p);
        Bc[n * 2 + 1] = *reinterpret_cast<const bf16x8*>(p + 32);
    }
    asm volatile("s_waitcnt vmcnt(12)" ::: "memory");   // drain A(0) only
    __builtin_amdgcn_s_barrier();

    int sA  = 0;   // t % 3
    int sA2 = 2;   // (t+2) % 3

    for (int t = 0; t < KT; ++t) {
        char* Ab = Abase + sA * A_SLOT;

        // -- stage A(t+2) -> LDS slot (t+2)%3 (slot last read in tile t-1;
        //    its readers retired before tile-(t-1)'s end barrier)
        if (t + 2 < KT) {
            char* An = Abase + sA2 * A_SLOT;
#pragma unroll
            for (int L = 0; L < 4; ++L)
                load_lds16(gA[L] + (size_t)(t + 2) * 64, An + dOff[L]);
        }

#pragma unroll
        for (int ks = 0; ks < 2; ++ks) {
            const int kb = k0 ^ (ks << 6);
            {   // rows 0..3 of this wave's 128-row span
                bf16x8 af[4];
#pragma unroll
                for (int m = 0; m < 4; ++m) {
                    const int r = wr * 128 + m * 16 + frow;
                    af[m] = *reinterpret_cast<const bf16x8*>(Ab + r * 128 + kb);
                }
                __builtin_amdgcn_s_setprio(1);
#pragma unroll
                for (int m = 0; m < 4; ++m) {
                    acc[m][0] = __builtin_amdgcn_mfma_f32_16x16x32_bf16(
                        af[m], Bc[0 + ks], acc[m][0], 0, 0, 0);
                    acc[m][1] = __builtin_amdgcn_mfma_f32_16x16x32_bf16(
                        af[m], Bc[2 + ks], acc[m][1], 0, 0, 0);
                    acc[m][2] = __builtin_amdgcn_mfma_f32_16x16x32_bf16(
                        af[m], Bc[4 + ks], acc[m][2], 0, 0, 0);
                    acc[m][3] = __builtin_amdgcn_mfma_f32_16x16x32_bf16(
                        af[m], Bc[6 + ks], acc[m][3], 0, 0, 0);
                }
                __builtin_amdgcn_s_setprio(0);
            }
            {   // rows 4..7
                bf16x8 ag[4];
#pragma unroll
                for (int m = 0; m < 4; ++m) {
                    const int r = wr * 128 + (m + 4) * 16 + frow;
                    ag[m] = *reinterpret_cast<const bf16x8*>(Ab + r * 128 + kb);
                }
                __builtin_amdgcn_s_setprio(1);
#pragma unroll
                for (int m = 0; m < 4; ++m) {
                    acc[m + 4][0] = __builtin_amdgcn_mfma_f32_16x16x32_bf16(
                        ag[m], Bc[0 + ks], acc[m + 4][0], 0, 0, 0);
                    acc[m + 4][1] = __builtin_amdgcn_mfma_f32_16x16x32_bf16(
                        ag[m], Bc[2 + ks], acc[m + 4][1], 0, 0, 0);
                    acc[m + 4][2] = __builtin_amdgcn_mfma_f32_16x16x32_bf16(
                        ag[m], Bc[4 + ks], acc[m + 4][2], 0, 0, 0);
                    acc[m + 4][3] = __builtin_amdgcn_mfma_f32_16x16x32_bf16(
                        ag[m], Bc[6 + ks], acc[m + 4][3], 0, 0, 0);
                }
                __builtin_amdgcn_s_setprio(0);
            }
        }

        // -- issue B(t+1) into the SAME Bc regs (WAR after last use above);
        //    stays in flight across the barrier, retires inside tile t+1.
        if (t + 1 < KT) {
#pragma unroll
            for (int n = 0; n < 4; ++n) {
                const short* p = gBf + (size_t)n * 16 * IN_F + (size_t)(t + 1) * 64;
                Bc[n * 2]     = *reinterpret_cast<const bf16x8*>(p);
                Bc[n * 2 + 1] = *reinterpret_cast<const bf16x8*>(p + 32);
            }
        }

        __builtin_amdgcn_s_barrier();   // no vm drain: loads span the barrier

        sA  = (sA  < 2) ? sA  + 1 : 0;
        sA2 = (sA2 < 2) ? sA2 + 1 : 0;
    }

    // ---- epilogue: C/D layout col=lane&15, row=(lane>>4)*4+reg (verified)
    const int crow = (lane >> 4) * 4;
    const int ccol = lane & 15;
#pragma unroll
    for (int fm = 0; fm < 8; ++fm)
#pragma unroll
        for (int fn = 0; fn < 4; ++fn)
#pragma unroll
            for (int r = 0; r < 4; ++r) {
                const int row = row0 + wr * 128 + fm * 16 + crow + r;
                const int col = col0 + wc * 64 + fn * 16 + ccol;
                C[(size_t)row * OUT_F + col] = acc[fm][fn][r];
            }
}

// ============================================================================
// Fallback GEMM (round-1, verified): used only if ws too small for Xb
// ============================================================================
#define BM 128
#define BN 128
#define BK 64

__global__ __launch_bounds__(256, 2) void gemm_x_wt_kernel(
    const float* __restrict__ X,
    const short* __restrict__ WT,
    float* __restrict__ C)
{
    __shared__ short As2[BM * BK];
    __shared__ short Bs2[BN * BK];

    const int bn = blockIdx.x;
    const int bm = blockIdx.y;
    const int tid  = threadIdx.x;
    const int lane = tid & 63;
    const int wid  = tid >> 6;
    const int wr   = wid >> 1;
    const int wc   = wid & 1;

    const int row0 = bm * BM;
    const int col0 = bn * BN;
    const int frow = lane & 15;
    const int fk   = (lane >> 4) * 8;

    f32x4 acc[4][4] = {};

    for (int kt = 0; kt < IN_F / BK; ++kt) {
        float4 a0[4], a1[4];
#pragma unroll
        for (int j = 0; j < 4; ++j) {
            const int flat = (j * 256 + tid) * 8;
            const int r = flat >> 6;
            const int c = flat & (BK - 1);
            const float* src = X + (size_t)(row0 + r) * IN_F + kt * BK + c;
            a0[j] = *reinterpret_cast<const float4*>(src);
            a1[j] = *reinterpret_cast<const float4*>(src + 4);
        }
        __syncthreads();
#pragma unroll
        for (int j = 0; j < 4; ++j) {
            const int flat = (j * 256 + tid) * 8;
            const int r = flat >> 6;
            const int c = flat & (BK - 1);
            load_lds16(WT + (size_t)(col0 + r) * IN_F + kt * BK + c, &Bs2[flat]);
        }
#pragma unroll
        for (int j = 0; j < 4; ++j) {
            const int flat = (j * 256 + tid) * 8;
            bf16x8 h;
            h[0] = f2bf(a0[j].x); h[1] = f2bf(a0[j].y);
            h[2] = f2bf(a0[j].z); h[3] = f2bf(a0[j].w);
            h[4] = f2bf(a1[j].x); h[5] = f2bf(a1[j].y);
            h[6] = f2bf(a1[j].z); h[7] = f2bf(a1[j].w);
            *reinterpret_cast<bf16x8*>(&As2[flat]) = h;
        }
        __syncthreads();
#pragma unroll
        for (int s = 0; s < 2; ++s) {
            bf16x8 af[4], bfr[4];
#pragma unroll
            for (int m = 0; m < 4; ++m) {
                const int row = wr * 64 + m * 16 + frow;
                af[m] = *reinterpret_cast<const bf16x8*>(&As2[row * BK + s * 32 + fk]);
            }
#pragma unroll
            for (int n = 0; n < 4; ++n) {
                const int col = wc * 64 + n * 16 + frow;
                bfr[n] = *reinterpret_cast<const bf16x8*>(&Bs2[col * BK + s * 32 + fk]);
            }
#pragma unroll
            for (int m = 0; m < 4; ++m)
#pragma unroll
                for (int n = 0; n < 4; ++n)
                    acc[m][n] = __builtin_amdgcn_mfma_f32_16x16x32_bf16(
                        af[m], bfr[n], acc[m][n], 0, 0, 0);
        }
    }

    const int crow = (lane >> 4) * 4;
    const int ccol = lane & 15;
#pragma unroll
    for (int m = 0; m < 4; ++m)
#pragma unroll
        for (int n = 0; n < 4; ++n)
#pragma unroll
            for (int r = 0; r < 4; ++r) {
                const int row = row0 + wr * 64 + m * 16 + crow + r;
                const int col = col0 + wc * 64 + n * 16 + ccol;
                C[(size_t)row * OUT_F + col] = acc[m][n][r];
            }
}

// ============================================================================
extern "C" void kernel_launch(void* const* d_in, const int* in_sizes, int n_in,
                              void* d_out, int out_size, void* d_ws, size_t ws_size,
                              hipStream_t stream) {
    const float* x       = (const float*)d_in[0];
    const int*   qweight = (const int*)  d_in[1];
    const int*   qzeros  = (const int*)  d_in[2];
    const float* scales  = (const float*)d_in[3];
    float*       out     = (float*)d_out;

    const size_t WT_BYTES = (size_t)OUT_F * IN_F * 2;   // 33.5 MB
    const size_t XB_BYTES = (size_t)M_ROWS * IN_F * 2;  // 67.1 MB

    short* wt = (short*)d_ws;

    dequant_wt_kernel<<<(OUT_F * (IN_F / 8)) / 256, 256, 0, stream>>>(
        qweight, qzeros, scales, wt);

    if (ws_size >= WT_BYTES + XB_BYTES) {
        short* xb = (short*)((char*)d_ws + WT_BYTES);
        xconv_kernel<<<(M_ROWS * IN_F / 8) / 256, 256, 0, stream>>>(x, xb);
        gemm8_kernel<<<(M_ROWS / 256) * (OUT_F / 256), 512, 0, stream>>>(xb, wt, out);
    } else {
        dim3 grid(OUT_F / BN, M_ROWS / BM);
        gemm_x_wt_kernel<<<grid, 256, 0, stream>>>(x, wt, out);
    }
}

// Round 8
// 381.286 us; speedup vs baseline: 2.1008x; 1.0935x over previous
//
#include <hip/hip_runtime.h>
#include <stdint.h>

// Problem constants
#define IN_F   4096
#define OUT_F  4096
#define M_ROWS 8192      // 4 * 2048
#define KT     (IN_F / 64)   // 64 K-tiles of BK=64

typedef __attribute__((ext_vector_type(8))) short  bf16x8;
typedef __attribute__((ext_vector_type(4))) float  f32x4;

__device__ __forceinline__ short f2bf(float f) {
    union { float f; uint32_t u; } v; v.f = f;
    uint32_t r = v.u + 0x7FFFu + ((v.u >> 16) & 1u);
    return (short)(r >> 16);
}

__device__ __forceinline__ void load_lds16(const void* gsrc, void* lds) {
    __builtin_amdgcn_global_load_lds(
        (const __attribute__((address_space(1))) uint32_t*)gsrc,
        (__attribute__((address_space(3))) uint32_t*)lds,
        16, 0, 0);
}

// ============================================================================
// Kernel 1: GPTQ dequant -> W^T bf16 [OUT_F][IN_F]   (unchanged, verified)
// ============================================================================
__global__ void dequant_wt_kernel(const int* __restrict__ qweight,
                                  const int* __restrict__ qzeros,
                                  const float* __restrict__ scales,
                                  short* __restrict__ wt)
{
    int t  = blockIdx.x * blockDim.x + threadIdx.x;
    int n  = t >> 9;
    int kw = t & 511;
    int g  = kw >> 4;

    float s = scales[g * OUT_F + n];
    uint32_t zw = (uint32_t)qzeros[g * (OUT_F / 8) + (n >> 3)];
    float z1 = (float)((zw >> (4 * (n & 7))) & 0xFu) + 1.0f;
    uint32_t q = (uint32_t)qweight[kw * OUT_F + n];

    bf16x8 out;
#pragma unroll
    for (int i = 0; i < 8; ++i) {
        float w = s * ((float)((q >> (4 * i)) & 0xFu) - z1);
        out[i] = f2bf(w);
    }
    *reinterpret_cast<bf16x8*>(&wt[(size_t)n * IN_F + kw * 8]) = out;
}

// ============================================================================
// Kernel 2: 256x256 GEMM, r4 K-loop structure (verified best: 237us, 53% Mfma)
//   + FUSED X fp32->bf16 conversion in A-staging (removes the 26us xconv pass).
//   A: 2-slot LDS; staged via regs: issue x f32 loads early, cvt+ds_write late
//      (T14). Same pre-swizzled source column + linear dest => identical LDS
//      layout to r2-r7 (verified, 0 bank conflicts).
//   B: 2-slot LDS via global_load_lds (r4 path).
//   vmcnt ledger now IMPLICIT: per tile issue order is B(t+1) glds first, then
//   x-batch0, then x-batch1; the cvt's register dep on batch1 (waited mid-tile)
//   retires everything older in-order => B(t+1) landed before the end barrier.
//   No explicit vmcnt; loads never drained at issue time.
//   End of tile: lgkmcnt(0) (publish ds_writes) + s_barrier.
//   Reg budget (256 unified cap at 8-wave blocks): acc 128 AGPR + ~115 VGPR.
// ============================================================================
#define A_SLOT 32768
#define B_SLOT 32768

__global__ __launch_bounds__(512, 2) void gemm8_kernel(
    const float* __restrict__ X,    // [M_ROWS][IN_F] fp32
    const short* __restrict__ WT,   // [OUT_F][IN_F] bf16
    float* __restrict__ C)          // [M_ROWS][OUT_F]
{
    __shared__ short AsBuf[2 * 256 * 64];   // 64 KB
    __shared__ short BsBuf[2 * 256 * 64];   // 64 KB
    char* const Abase = (char*)AsBuf;
    char* const Bbase = (char*)BsBuf;

    const int tid  = threadIdx.x;
    const int lane = tid & 63;
    const int wid  = tid >> 6;     // 0..7
    const int wr   = wid >> 2;     // 0..1  (M half)
    const int wc   = wid & 3;      // 0..3  (N quarter)

    const int row0 = blockIdx.y * 256;
    const int col0 = blockIdx.x * 256;

    // ---- staging geometry (verified r2-r7): pre-swizzled source col (rule 21),
    //      linear LDS dest. Thread covers slot bytes [L*8192 + tid*16).
    const int rL0 = tid >> 3;
    const int csw = ((tid & 7) << 3) ^ ((rL0 & 7) << 3);
    const float* gAx[4]; const short* gB[4]; int dOff[4];
#pragma unroll
    for (int L = 0; L < 4; ++L) {
        gAx[L] = X  + (size_t)(row0 + L * 64 + rL0) * IN_F + csw;
        gB[L]  = WT + (size_t)(col0 + L * 64 + rL0) * IN_F + csw;
        dOff[L] = L * 8192 + tid * 16;
    }

    // ---- read geometry (verified): frag(ks) at byte k0 ^ (ks<<6)
    const int frow = lane & 15;
    const int k0   = ((lane >> 4) << 4) ^ ((frow & 7) << 4);

    f32x4 acc[8][4] = {};

    // ---- prologue: B(0) -> Bs[0] (async); A(0) reg-staged + cvt -> As[0]
#pragma unroll
    for (int L = 0; L < 4; ++L) load_lds16(gB[L], Bbase + 0 * B_SLOT + dOff[L]);
#pragma unroll
    for (int L = 0; L < 4; ++L) {
        const float* p = gAx[L];
        float4 a = *reinterpret_cast<const float4*>(p);
        float4 b = *reinterpret_cast<const float4*>(p + 4);
        bf16x8 h;
        h[0] = f2bf(a.x); h[1] = f2bf(a.y); h[2] = f2bf(a.z); h[3] = f2bf(a.w);
        h[4] = f2bf(b.x); h[5] = f2bf(b.y); h[6] = f2bf(b.z); h[7] = f2bf(b.w);
        *reinterpret_cast<bf16x8*>(Abase + dOff[L]) = h;
    }
    asm volatile("s_waitcnt vmcnt(0) lgkmcnt(0)" ::: "memory");
    __builtin_amdgcn_s_barrier();

    for (int t = 0; t < KT; ++t) {
        char* Ab = Abase + (t & 1) * A_SLOT;
        char* Bb = Bbase + (t & 1) * B_SLOT;
        char* An = Abase + ((t + 1) & 1) * A_SLOT;
        char* Bn = Bbase + ((t + 1) & 1) * B_SLOT;
        const bool pf = (t + 1 < KT);

        // -- 1) B(t+1) -> LDS (issued FIRST: oldest in vm queue)
        if (pf) {
#pragma unroll
            for (int L = 0; L < 4; ++L)
                load_lds16(gB[L] + (size_t)(t + 1) * 64, Bn + dOff[L]);
        }
        // -- 2) x batch0 (L=0,1) for A(t+1) -> regs
        float4 x0a, x0b, x1a, x1b;
        if (pf) {
            const float* p0 = gAx[0] + (size_t)(t + 1) * 64;
            const float* p1 = gAx[1] + (size_t)(t + 1) * 64;
            x0a = *reinterpret_cast<const float4*>(p0);
            x0b = *reinterpret_cast<const float4*>(p0 + 4);
            x1a = *reinterpret_cast<const float4*>(p1);
            x1b = *reinterpret_cast<const float4*>(p1 + 4);
        }

        // -- 3) ks=0: ds_read + 32 MFMA (scoped af/ag halves for reg budget)
        {
            const int kb = k0;
            bf16x8 bfr[4];
#pragma unroll
            for (int n = 0; n < 4; ++n) {
                const int r = wc * 64 + n * 16 + frow;
                bfr[n] = *reinterpret_cast<const bf16x8*>(Bb + r * 128 + kb);
            }
            {
                bf16x8 af[4];
#pragma unroll
                for (int m = 0; m < 4; ++m) {
                    const int r = wr * 128 + m * 16 + frow;
                    af[m] = *reinterpret_cast<const bf16x8*>(Ab + r * 128 + kb);
                }
                __builtin_amdgcn_s_setprio(1);
#pragma unroll
                for (int m = 0; m < 4; ++m)
#pragma unroll
                    for (int n = 0; n < 4; ++n)
                        acc[m][n] = __builtin_amdgcn_mfma_f32_16x16x32_bf16(
                            af[m], bfr[n], acc[m][n], 0, 0, 0);
                __builtin_amdgcn_s_setprio(0);
            }
            {
                bf16x8 ag[4];
#pragma unroll
                for (int m = 0; m < 4; ++m) {
                    const int r = wr * 128 + (m + 4) * 16 + frow;
                    ag[m] = *reinterpret_cast<const bf16x8*>(Ab + r * 128 + kb);
                }
                __builtin_amdgcn_s_setprio(1);
#pragma unroll
                for (int m = 0; m < 4; ++m)
#pragma unroll
                    for (int n = 0; n < 4; ++n)
                        acc[m + 4][n] = __builtin_amdgcn_mfma_f32_16x16x32_bf16(
                            ag[m], bfr[n], acc[m + 4][n], 0, 0, 0);
                __builtin_amdgcn_s_setprio(0);
            }
        }

        // -- 4) cvt+write batch0 (x loads have had a full MFMA block to land);
        //       issue x batch1 (L=2,3)
        float4 x2a, x2b, x3a, x3b;
        if (pf) {
            bf16x8 h0, h1;
            h0[0] = f2bf(x0a.x); h0[1] = f2bf(x0a.y); h0[2] = f2bf(x0a.z); h0[3] = f2bf(x0a.w);
            h0[4] = f2bf(x0b.x); h0[5] = f2bf(x0b.y); h0[6] = f2bf(x0b.z); h0[7] = f2bf(x0b.w);
            h1[0] = f2bf(x1a.x); h1[1] = f2bf(x1a.y); h1[2] = f2bf(x1a.z); h1[3] = f2bf(x1a.w);
            h1[4] = f2bf(x1b.x); h1[5] = f2bf(x1b.y); h1[6] = f2bf(x1b.z); h1[7] = f2bf(x1b.w);
            *reinterpret_cast<bf16x8*>(An + dOff[0]) = h0;
            *reinterpret_cast<bf16x8*>(An + dOff[1]) = h1;
            const float* p2 = gAx[2] + (size_t)(t + 1) * 64;
            const float* p3 = gAx[3] + (size_t)(t + 1) * 64;
            x2a = *reinterpret_cast<const float4*>(p2);
            x2b = *reinterpret_cast<const float4*>(p2 + 4);
            x3a = *reinterpret_cast<const float4*>(p3);
            x3b = *reinterpret_cast<const float4*>(p3 + 4);
        }

        // -- 5) ks=1: ds_read + 32 MFMA
        {
            const int kb = k0 ^ 64;
            bf16x8 bfr[4];
#pragma unroll
            for (int n = 0; n < 4; ++n) {
                const int r = wc * 64 + n * 16 + frow;
                bfr[n] = *reinterpret_cast<const bf16x8*>(Bb + r * 128 + kb);
            }
            {
                bf16x8 af[4];
#pragma unroll
                for (int m = 0; m < 4; ++m) {
                    const int r = wr * 128 + m * 16 + frow;
                    af[m] = *reinterpret_cast<const bf16x8*>(Ab + r * 128 + kb);
                }
                __builtin_amdgcn_s_setprio(1);
#pragma unroll
                for (int m = 0; m < 4; ++m)
#pragma unroll
                    for (int n = 0; n < 4; ++n)
                        acc[m][n] = __builtin_amdgcn_mfma_f32_16x16x32_bf16(
                            af[m], bfr[n], acc[m][n], 0, 0, 0);
                __builtin_amdgcn_s_setprio(0);
            }
            {
                bf16x8 ag[4];
#pragma unroll
                for (int m = 0; m < 4; ++m) {
                    const int r = wr * 128 + (m + 4) * 16 + frow;
                    ag[m] = *reinterpret_cast<const bf16x8*>(Ab + r * 128 + kb);
                }
                __builtin_amdgcn_s_setprio(1);
#pragma unroll
                for (int m = 0; m < 4; ++m)
#pragma unroll
                    for (int n = 0; n < 4; ++n)
                        acc[m + 4][n] = __builtin_amdgcn_mfma_f32_16x16x32_bf16(
                            ag[m], bfr[n], acc[m + 4][n], 0, 0, 0);
                __builtin_amdgcn_s_setprio(0);
            }
        }

        // -- 6) cvt+write batch1 (reg dep here also retires B(t+1): in-order)
        if (pf) {
            bf16x8 h2, h3;
            h2[0] = f2bf(x2a.x); h2[1] = f2bf(x2a.y); h2[2] = f2bf(x2a.z); h2[3] = f2bf(x2a.w);
            h2[4] = f2bf(x2b.x); h2[5] = f2bf(x2b.y); h2[6] = f2bf(x2b.z); h2[7] = f2bf(x2b.w);
            h3[0] = f2bf(x3a.x); h3[1] = f2bf(x3a.y); h3[2] = f2bf(x3a.z); h3[3] = f2bf(x3a.w);
            h3[4] = f2bf(x3b.x); h3[5] = f2bf(x3b.y); h3[6] = f2bf(x3b.z); h3[7] = f2bf(x3b.w);
            *reinterpret_cast<bf16x8*>(An + dOff[2]) = h2;
            *reinterpret_cast<bf16x8*>(An + dOff[3]) = h3;
        }

        // -- 7) publish ds_writes, rendezvous. No vm drain (implicit ledger).
        asm volatile("s_waitcnt lgkmcnt(0)" ::: "memory");
        __builtin_amdgcn_s_barrier();
    }

    // ---- epilogue: C/D layout col=lane&15, row=(lane>>4)*4+reg (verified)
    const int crow = (lane >> 4) * 4;
    const int ccol = lane & 15;
#pragma unroll
    for (int fm = 0; fm < 8; ++fm)
#pragma unroll
        for (int fn = 0; fn < 4; ++fn)
#pragma unroll
            for (int r = 0; r < 4; ++r) {
                const int row = row0 + wr * 128 + fm * 16 + crow + r;
                const int col = col0 + wc * 64 + fn * 16 + ccol;
                C[(size_t)row * OUT_F + col] = acc[fm][fn][r];
            }
}

// ============================================================================
extern "C" void kernel_launch(void* const* d_in, const int* in_sizes, int n_in,
                              void* d_out, int out_size, void* d_ws, size_t ws_size,
                              hipStream_t stream) {
    const float* x       = (const float*)d_in[0];
    const int*   qweight = (const int*)  d_in[1];
    const int*   qzeros  = (const int*)  d_in[2];
    const float* scales  = (const float*)d_in[3];
    float*       out     = (float*)d_out;

    short* wt = (short*)d_ws;   // W^T bf16 [OUT_F][IN_F] = 33.5 MB

    dequant_wt_kernel<<<(OUT_F * (IN_F / 8)) / 256, 256, 0, stream>>>(
        qweight, qzeros, scales, wt);

    dim3 grid(OUT_F / 256, M_ROWS / 256);   // (16, 32)
    gemm8_kernel<<<grid, 512, 0, stream>>>(x, wt, out);
}

// Round 9
// 271.963 us; speedup vs baseline: 2.9452x; 1.4020x over previous
//
#include <hip/hip_runtime.h>
#include <stdint.h>

// Problem constants
#define IN_F   4096
#define OUT_F  4096
#define M_ROWS 8192      // 4 * 2048
#define KT     (IN_F / 64)   // 64 K-tiles of BK=64

typedef __attribute__((ext_vector_type(8))) short  bf16x8;
typedef __attribute__((ext_vector_type(4))) float  f32x4;

__device__ __forceinline__ short f2bf(float f) {
    union { float f; uint32_t u; } v; v.f = f;
    uint32_t r = v.u + 0x7FFFu + ((v.u >> 16) & 1u);
    return (short)(r >> 16);
}

__device__ __forceinline__ void load_lds16(const void* gsrc, void* lds) {
    __builtin_amdgcn_global_load_lds(
        (const __attribute__((address_space(1))) uint32_t*)gsrc,
        (__attribute__((address_space(3))) uint32_t*)lds,
        16, 0, 0);
}

// ============================================================================
// Kernel 1: FUSED prepass — dequant (blocks [0, DQ_BLOCKS)) and X fp32->bf16
// conversion (blocks [DQ_BLOCKS, DQ_BLOCKS+XC_BLOCKS)). Branch is
// block-uniform; both sides are BW-bound and independent.
// ============================================================================
#define DQ_BLOCKS ((OUT_F * (IN_F / 8)) / 256)      // 8192
#define XC_BLOCKS ((M_ROWS * IN_F / 8) / 256)       // 16384

__global__ void prepass_kernel(const int* __restrict__ qweight,
                               const int* __restrict__ qzeros,
                               const float* __restrict__ scales,
                               const float* __restrict__ x,
                               short* __restrict__ wt,
                               short* __restrict__ xb)
{
    const int bid = blockIdx.x;
    if (bid < DQ_BLOCKS) {
        // ---- GPTQ dequant -> W^T bf16 [OUT_F][IN_F]  (verified r1-r8)
        int t  = bid * 256 + threadIdx.x;
        int n  = t >> 9;
        int kw = t & 511;
        int g  = kw >> 4;

        float s = scales[g * OUT_F + n];
        uint32_t zw = (uint32_t)qzeros[g * (OUT_F / 8) + (n >> 3)];
        float z1 = (float)((zw >> (4 * (n & 7))) & 0xFu) + 1.0f;
        uint32_t q = (uint32_t)qweight[kw * OUT_F + n];

        bf16x8 out;
#pragma unroll
        for (int i = 0; i < 8; ++i) {
            float w = s * ((float)((q >> (4 * i)) & 0xFu) - z1);
            out[i] = f2bf(w);
        }
        *reinterpret_cast<bf16x8*>(&wt[(size_t)n * IN_F + kw * 8]) = out;
    } else {
        // ---- X fp32 -> bf16  (verified r2-r7)
        int t = (bid - DQ_BLOCKS) * 256 + threadIdx.x;
        const float4* src = reinterpret_cast<const float4*>(x) + (size_t)t * 2;
        float4 a = src[0], b = src[1];
        bf16x8 h;
        h[0] = f2bf(a.x); h[1] = f2bf(a.y); h[2] = f2bf(a.z); h[3] = f2bf(a.w);
        h[4] = f2bf(b.x); h[5] = f2bf(b.y); h[6] = f2bf(b.z); h[7] = f2bf(b.w);
        reinterpret_cast<bf16x8*>(xb)[t] = h;
    }
}

// ============================================================================
// Kernel 2: 256x256 GEMM — EXACT r4 structure (measured best: 237us GEMM,
// 1.16 PF, MfmaUtil 53%, 0 bank conflicts).
//   LDS: A x3 slots (96KB) + B x2 slots (64KB) = 160KB
//   Per tile t: stage B(t+1), A(t+2); end-of-tile: vmcnt(4) + s_barrier
//   Phase ks (ks=0,1): 12 ds_read_b128 (8 A-frags + 4 B-frags, each read ONCE)
//                      then 32 MFMA (8m x 4n). One barrier per K-tile.
//   T2 swizzle identical to r2-r4.
// ============================================================================
#define A_SLOT 32768
#define B_SLOT 32768

__global__ __launch_bounds__(512, 1) void gemm8_kernel(
    const short* __restrict__ Xb,   // [M_ROWS][IN_F] bf16
    const short* __restrict__ WT,   // [OUT_F][IN_F] bf16
    float* __restrict__ C)          // [M_ROWS][OUT_F]
{
    __shared__ short AsBuf[3 * 256 * 64];   // 96 KB
    __shared__ short BsBuf[2 * 256 * 64];   // 64 KB
    char* const Abase = (char*)AsBuf;
    char* const Bbase = (char*)BsBuf;

    const int tid  = threadIdx.x;
    const int lane = tid & 63;
    const int wid  = tid >> 6;     // 0..7
    const int wr   = wid >> 2;     // 0..1  (M half)
    const int wc   = wid & 3;      // 0..3  (N quarter)

    const int row0 = blockIdx.y * 256;
    const int col0 = blockIdx.x * 256;

    // ---- staging geometry (verified r2-r4): load L covers slot bytes
    //      [L*8192 + tid*16, +16); source col pre-swizzled (rule 21)
    const int rL0 = tid >> 3;
    const int csw = ((tid & 7) << 3) ^ ((rL0 & 7) << 3);
    const short* gA[4]; const short* gB[4]; int dOff[4];
#pragma unroll
    for (int L = 0; L < 4; ++L) {
        const int r = L * 64 + rL0;
        gA[L] = Xb + (size_t)(row0 + r) * IN_F + csw;
        gB[L] = WT + (size_t)(col0 + r) * IN_F + csw;
        dOff[L] = L * 8192 + tid * 16;
    }

    // ---- read geometry (verified r2-r4); frag(ks) at byte k0 ^ (ks<<6)
    const int frow = lane & 15;
    const int k0   = ((lane >> 4) << 4) ^ ((frow & 7) << 4);

    f32x4 acc[8][4] = {};

    // ---- prologue: issue A(0), B(0), A(1); wait A0+B0; leave A1 in flight
#pragma unroll
    for (int L = 0; L < 4; ++L) load_lds16(gA[L],      Abase + 0 * A_SLOT + dOff[L]);
#pragma unroll
    for (int L = 0; L < 4; ++L) load_lds16(gB[L],      Bbase + 0 * B_SLOT + dOff[L]);
#pragma unroll
    for (int L = 0; L < 4; ++L) load_lds16(gA[L] + 64, Abase + 1 * A_SLOT + dOff[L]);
    asm volatile("s_waitcnt vmcnt(4)" ::: "memory");
    __builtin_amdgcn_s_barrier();

    int sA = 0;   // A slot of tile t   (t % 3)
    int sB = 0;   // B slot of tile t   (t & 1)

    for (int t = 0; t < KT; ++t) {
        char* Ab = Abase + sA * A_SLOT;
        char* Bb = Bbase + sB * B_SLOT;
        const int sA2 = (sA >= 1) ? sA - 1 : 2;       // (t+2) % 3
        char* An = Abase + sA2 * A_SLOT;
        char* Bn = Bbase + (sB ^ 1) * B_SLOT;
        const bool pfB = (t + 1 < KT);
        const bool pfA = (t + 2 < KT);

#pragma unroll
        for (int ks = 0; ks < 2; ++ks) {
            const int kb = k0 ^ (ks << 6);

            // -- 12 ds_read_b128: every fragment of this K-half, read once
            bf16x8 af[8]; bf16x8 bfr[4];
#pragma unroll
            for (int m = 0; m < 8; ++m) {
                const int r = wr * 128 + m * 16 + frow;
                af[m] = *reinterpret_cast<const bf16x8*>(Ab + r * 128 + kb);
            }
#pragma unroll
            for (int n = 0; n < 4; ++n) {
                const int r = wc * 64 + n * 16 + frow;
                bfr[n] = *reinterpret_cast<const bf16x8*>(Bb + r * 128 + kb);
            }

            // -- staging issued once per tile, overlapped with phase-0 compute
            if (ks == 0) {
                if (pfB) {
#pragma unroll
                    for (int L = 0; L < 4; ++L)
                        load_lds16(gB[L] + (size_t)(t + 1) * 64, Bn + dOff[L]);
                }
                if (pfA) {
#pragma unroll
                    for (int L = 0; L < 4; ++L)
                        load_lds16(gA[L] + (size_t)(t + 2) * 64, An + dOff[L]);
                }
            }

            // -- 32 MFMA; compiler inserts its own counted lgkm waits
            __builtin_amdgcn_s_setprio(1);
#pragma unroll
            for (int m = 0; m < 8; ++m)
#pragma unroll
                for (int n = 0; n < 4; ++n)
                    acc[m][n] = __builtin_amdgcn_mfma_f32_16x16x32_bf16(
                        af[m], bfr[n], acc[m][n], 0, 0, 0);
            __builtin_amdgcn_s_setprio(0);
        }

        // -- ONE barrier per K-tile, counted vmcnt (A(t+2) stays in flight)
        if (t < KT - 2)       asm volatile("s_waitcnt vmcnt(4)" ::: "memory");
        else if (t == KT - 2) asm volatile("s_waitcnt vmcnt(0)" ::: "memory");
        __builtin_amdgcn_s_barrier();

        sA = (sA < 2) ? sA + 1 : 0;
        sB ^= 1;
    }

    // ---- epilogue: C/D layout col=lane&15, row=(lane>>4)*4+reg (verified)
    const int crow = (lane >> 4) * 4;
    const int ccol = lane & 15;
#pragma unroll
    for (int fm = 0; fm < 8; ++fm)
#pragma unroll
        for (int fn = 0; fn < 4; ++fn)
#pragma unroll
            for (int r = 0; r < 4; ++r) {
                const int row = row0 + wr * 128 + fm * 16 + crow + r;
                const int col = col0 + wc * 64 + fn * 16 + ccol;
                C[(size_t)row * OUT_F + col] = acc[fm][fn][r];
            }
}

// ============================================================================
// Fallback GEMM (round-1, verified): used only if ws too small for Xb
// ============================================================================
#define BM 128
#define BN 128
#define BK 64

__global__ __launch_bounds__(256, 2) void gemm_x_wt_kernel(
    const float* __restrict__ X,
    const short* __restrict__ WT,
    float* __restrict__ C)
{
    __shared__ short As2[BM * BK];
    __shared__ short Bs2[BN * BK];

    const int bn = blockIdx.x;
    const int bm = blockIdx.y;
    const int tid  = threadIdx.x;
    const int lane = tid & 63;
    const int wid  = tid >> 6;
    const int wr   = wid >> 1;
    const int wc   = wid & 1;

    const int row0 = bm * BM;
    const int col0 = bn * BN;
    const int frow = lane & 15;
    const int fk   = (lane >> 4) * 8;

    f32x4 acc[4][4] = {};

    for (int kt = 0; kt < IN_F / BK; ++kt) {
        float4 a0[4], a1[4];
#pragma unroll
        for (int j = 0; j < 4; ++j) {
            const int flat = (j * 256 + tid) * 8;
            const int r = flat >> 6;
            const int c = flat & (BK - 1);
            const float* src = X + (size_t)(row0 + r) * IN_F + kt * BK + c;
            a0[j] = *reinterpret_cast<const float4*>(src);
            a1[j] = *reinterpret_cast<const float4*>(src + 4);
        }
        __syncthreads();
#pragma unroll
        for (int j = 0; j < 4; ++j) {
            const int flat = (j * 256 + tid) * 8;
            const int r = flat >> 6;
            const int c = flat & (BK - 1);
            load_lds16(WT + (size_t)(col0 + r) * IN_F + kt * BK + c, &Bs2[flat]);
        }
#pragma unroll
        for (int j = 0; j < 4; ++j) {
            const int flat = (j * 256 + tid) * 8;
            bf16x8 h;
            h[0] = f2bf(a0[j].x); h[1] = f2bf(a0[j].y);
            h[2] = f2bf(a0[j].z); h[3] = f2bf(a0[j].w);
            h[4] = f2bf(a1[j].x); h[5] = f2bf(a1[j].y);
            h[6] = f2bf(a1[j].z); h[7] = f2bf(a1[j].w);
            *reinterpret_cast<bf16x8*>(&As2[flat]) = h;
        }
        __syncthreads();
#pragma unroll
        for (int s = 0; s < 2; ++s) {
            bf16x8 af[4], bfr[4];
#pragma unroll
            for (int m = 0; m < 4; ++m) {
                const int row = wr * 64 + m * 16 + frow;
                af[m] = *reinterpret_cast<const bf16x8*>(&As2[row * BK + s * 32 + fk]);
            }
#pragma unroll
            for (int n = 0; n < 4; ++n) {
                const int col = wc * 64 + n * 16 + frow;
                bfr[n] = *reinterpret_cast<const bf16x8*>(&Bs2[col * BK + s * 32 + fk]);
            }
#pragma unroll
            for (int m = 0; m < 4; ++m)
#pragma unroll
                for (int n = 0; n < 4; ++n)
                    acc[m][n] = __builtin_amdgcn_mfma_f32_16x16x32_bf16(
                        af[m], bfr[n], acc[m][n], 0, 0, 0);
        }
    }

    const int crow = (lane >> 4) * 4;
    const int ccol = lane & 15;
#pragma unroll
    for (int m = 0; m < 4; ++m)
#pragma unroll
        for (int n = 0; n < 4; ++n)
#pragma unroll
            for (int r = 0; r < 4; ++r) {
                const int row = row0 + wr * 64 + m * 16 + crow + r;
                const int col = col0 + wc * 64 + n * 16 + ccol;
                C[(size_t)row * OUT_F + col] = acc[m][n][r];
            }
}

// ============================================================================
extern "C" void kernel_launch(void* const* d_in, const int* in_sizes, int n_in,
                              void* d_out, int out_size, void* d_ws, size_t ws_size,
                              hipStream_t stream) {
    const float* x       = (const float*)d_in[0];
    const int*   qweight = (const int*)  d_in[1];
    const int*   qzeros  = (const int*)  d_in[2];
    const float* scales  = (const float*)d_in[3];
    float*       out     = (float*)d_out;

    const size_t WT_BYTES = (size_t)OUT_F * IN_F * 2;   // 33.5 MB
    const size_t XB_BYTES = (size_t)M_ROWS * IN_F * 2;  // 67.1 MB

    short* wt = (short*)d_ws;

    if (ws_size >= WT_BYTES + XB_BYTES) {
        short* xb = (short*)((char*)d_ws + WT_BYTES);
        prepass_kernel<<<DQ_BLOCKS + XC_BLOCKS, 256, 0, stream>>>(
            qweight, qzeros, scales, x, wt, xb);
        dim3 grid(OUT_F / 256, M_ROWS / 256);   // (16, 32)
        gemm8_kernel<<<grid, 512, 0, stream>>>(xb, wt, out);
    } else {
        // dequant-only prepass blocks still produce wt correctly
        prepass_kernel<<<DQ_BLOCKS, 256, 0, stream>>>(
            qweight, qzeros, scales, x, wt, (short*)nullptr);
        dim3 grid(OUT_F / BN, M_ROWS / BM);
        gemm_x_wt_kernel<<<grid, 256, 0, stream>>>(x, wt, out);
    }
}